// Round 2
// 106.981 us; speedup vs baseline: 1.1393x; 1.1393x over previous
//
#include <hip/hip_runtime.h>
#include <hip/hip_bf16.h>
#include <stdint.h>

// Problem constants: B=IC=16, L=4096, OC=256, NC=8, CD=16, K=9
#define IK_ 144
typedef __fp16 h2    __attribute__((ext_vector_type(2)));
typedef __fp16 f16x8 __attribute__((ext_vector_type(8)));
typedef float  f32x4 __attribute__((ext_vector_type(4)));

// workspace layout (float/dword element offsets)
#define WS_CWH 0u          // folded conv->caps weights, fp16 [128 nk][160 k'] (k'=i*10+t, t=9 pad=0): 10240 dwords
#define WS_CB  10240u      // cb[128] fp32
#define WS_U   10368u      // u[b][nk][s] bf16 at ((uint16_t*)(ws+WS_U)) + ((b*128+nk)<<12)+s (16.7 MB)

__device__ __forceinline__ uint32_t pack2bf(float a, float b) {
    const uint32_t lo = (uint32_t)__bfloat16_as_ushort(__float2bfloat16(a));
    const uint32_t hi = (uint32_t)__bfloat16_as_ushort(__float2bfloat16(b));
    return lo | (hi << 16);
}
#define BFLO(u) __uint_as_float((u) << 16)
#define BFHI(u) __uint_as_float((u) & 0xffff0000u)

// ---------------- K0: folded conv->caps weights, fp16 [nk][k'=i*10+t] (t=9 zero pad) ----------------
// cw[nk,i*9+t] = sum_c caps_w[nk,c]*conv_w[c,i*9+t]
__global__ void k_cw(const float* __restrict__ caps_w,
                     const float* __restrict__ conv_w,
                     const float* __restrict__ conv_b,
                     const float* __restrict__ caps_b,
                     float* __restrict__ ws) {
    __shared__ float cwl[256];
    __shared__ float cwf[IK_];
    const int nk  = blockIdx.x;
    const int tid = threadIdx.x;
    cwl[tid] = caps_w[nk*256 + tid];
    __syncthreads();
    if (tid < IK_) {
        float a0 = 0.f, a1 = 0.f, a2 = 0.f, a3 = 0.f;
        for (int c = 0; c < 256; c += 4) {
            a0 += cwl[c+0] * conv_w[(c+0)*IK_ + tid];
            a1 += cwl[c+1] * conv_w[(c+1)*IK_ + tid];
            a2 += cwl[c+2] * conv_w[(c+2)*IK_ + tid];
            a3 += cwl[c+3] * conv_w[(c+3)*IK_ + tid];
        }
        cwf[tid] = (a0 + a1) + (a2 + a3);
    } else if (tid == IK_) {
        float a = 0.f;
        for (int c = 0; c < 256; ++c) a += cwl[c] * conv_b[c];
        ws[WS_CB + nk] = a + caps_b[nk];
    }
    __syncthreads();
    if (tid < 160) {                       // k' = i*10 + t, t in [0,10): t=9 is a zero-weight pad tap
        const int i = tid / 10;
        const int t = tid - 10*i;
        const float v = (t < 9) ? cwf[i*9 + t] : 0.f;
        ((uint16_t*)(ws + WS_CWH))[nk*160 + tid] = __builtin_bit_cast(uint16_t, (__fp16)v);
    }
}

// ---------------- K1: u[b,nk,s] via MFMA f32_16x16x32_f16 ----------------
// block = (b 0..15 | stile 0..31), 128 s per tile, all 128 nk per block.
// 4 waves, 2x2: wave tile = 64 nk x 64 s = 4x4 fragments of 16x16. K'=160 = 5 k-steps of 32.
// A = weights from LDS (row stride 168 halves, bank-spread). B built per-lane from raw x window
// (scalar LDS f32 reads + cvt_pkrtz) -- no im2col materialization.
__global__ void __launch_bounds__(256) k_conv(const float* __restrict__ x,
                                              const float* __restrict__ wsc,
                                              float* __restrict__ ws) {
    const int tid   = threadIdx.x;
    const int b     = blockIdx.x & 15;
    const int stile = blockIdx.x >> 4;
    const int sbase = stile << 7;

    __shared__ float  xs[16*140];      // row i, elem e <-> x[b,i, sbase-4+e], e in [0,137), OOB = 0
    __shared__ __fp16 aw[128*168];     // [nk][k'] padded row stride 168
    __shared__ float  cbl[128];

    // stage folded weights: 128 rows x 320 B; half-row (80 halves = 10 uint4) per thread
    {
        const int row = tid >> 1, hf = tid & 1;
        const uint4* src = (const uint4*)((const uint16_t*)(wsc + WS_CWH) + row*160 + hf*80);
        uint4* dst = (uint4*)(aw + row*168 + hf*80);
        #pragma unroll
        for (int j = 0; j < 10; ++j) dst[j] = src[j];   // FIX: was j<5 (staged only half the weights)
    }
    if (tid < 128) cbl[tid] = wsc[WS_CB + tid];

    // stage x window [sbase-4, sbase+136): 16 rows x 35 float4 (divide-free, zero OOB)
    {
        const int row = tid >> 4, c0 = tid & 15;
        const float* xr = x + (b << 16) + (row << 12);
        float* lr = xs + row*140;
        #pragma unroll
        for (int k3 = 0; k3 < 3; ++k3) {
            const int col = c0 + (k3 << 4);
            if (col < 35) {
                const int j0 = sbase - 4 + (col << 2);
                float4 v;
                if (j0 < 0 || j0 > 4092) v = make_float4(0.f, 0.f, 0.f, 0.f);
                else v = *(const float4*)(xr + j0);
                *(float4*)(lr + (col << 2)) = v;
            }
        }
    }
    __syncthreads();

    const int lane = tid & 63;
    const int wid  = tid >> 6;
    const int sub  = lane & 15;     // A-row / B-col within fragment
    const int g    = lane >> 4;     // k-chunk group (8 k each)
    const int wm   = wid >> 1;      // nk half (0,1)
    const int wn   = wid & 1;       // s half (0,1)

    f32x4 acc[4][4] = {};

    #pragma unroll
    for (int kb = 0; kb < 5; ++kb) {
        // A fragments: 8 contiguous halves per lane from row (nk), offset kb*32 + g*8
        f16x8 a[4];
        #pragma unroll
        for (int mi = 0; mi < 4; ++mi)
            a[mi] = *(const f16x8*)(aw + ((wm<<6) + (mi<<4) + sub)*168 + (kb<<5) + (g<<3));

        // per-lane x_lds offsets for this lane's 8 k' values (k' = i*10 + t)
        int offs[8];
        #pragma unroll
        for (int e = 0; e < 8; ++e) {
            const int kp = (kb<<5) + (g<<3) + e;
            const int i  = kp / 10;
            offs[e] = i*140 + (kp - 10*i);   // xs elem e = s_local + t
        }

        // B fragments: read 8 f32 from raw x window, pack to fp16 pairs (RTZ, same as old path)
        f16x8 bf[4];
        #pragma unroll
        for (int ni = 0; ni < 4; ++ni) {
            const int sl = (wn<<6) + (ni<<4) + sub;
            float f[8];
            #pragma unroll
            for (int e = 0; e < 8; ++e) f[e] = xs[offs[e] + sl];
            union { h2 h[4]; f16x8 v; } u;
            u.h[0] = __builtin_amdgcn_cvt_pkrtz(f[0], f[1]);
            u.h[1] = __builtin_amdgcn_cvt_pkrtz(f[2], f[3]);
            u.h[2] = __builtin_amdgcn_cvt_pkrtz(f[4], f[5]);
            u.h[3] = __builtin_amdgcn_cvt_pkrtz(f[6], f[7]);
            bf[ni] = u.v;
        }

        #pragma unroll
        for (int mi = 0; mi < 4; ++mi) {
            #pragma unroll
            for (int ni = 0; ni < 4; ++ni)
                acc[mi][ni] = __builtin_amdgcn_mfma_f32_16x16x32_f16(a[mi], bf[ni], acc[mi][ni], 0, 0, 0);
        }
    }

    // epilogue: C/D layout col(s)=lane&15, row(nk)=g*4+reg. Pair s-adjacent lanes via shfl_xor(1)
    // so each lane stores one bf16x2 dword (even lane -> rows j0/j2, odd lane -> rows j1/j3).
    // Consecutive ni fragments fill complete 128B lines per nk row -> write-combines cleanly.
    const int odd = sub & 1;
    uint32_t* uw = (uint32_t*)((uint16_t*)(ws + WS_U));
    #pragma unroll
    for (int mi = 0; mi < 4; ++mi) {
        const int nkb = (wm<<6) + (mi<<4) + (g<<2);
        const float cb0 = cbl[nkb+0], cb1 = cbl[nkb+1], cb2 = cbl[nkb+2], cb3 = cbl[nkb+3];
        #pragma unroll
        for (int ni = 0; ni < 4; ++ni) {
            const f32x4 v = acc[mi][ni];
            const uint32_t A01 = pack2bf(v.x + cb0, v.y + cb1);
            const uint32_t A23 = pack2bf(v.z + cb2, v.w + cb3);
            const uint32_t Q01 = (uint32_t)__shfl_xor((int)A01, 1);
            const uint32_t Q23 = (uint32_t)__shfl_xor((int)A23, 1);
            const uint32_t dA = odd ? ((Q01 >> 16) | (A01 & 0xffff0000u))
                                    : ((A01 & 0xffffu) | (Q01 << 16));
            const uint32_t dB = odd ? ((Q23 >> 16) | (A23 & 0xffff0000u))
                                    : ((A23 & 0xffffu) | (Q23 << 16));
            const int nkA = nkb + odd;                                 // row j0 or j1 (dB: +2)
            const int s0  = sbase + (wn<<6) + (ni<<4) + (sub & ~1);
            const size_t di = (((size_t)((b<<7) + nkA)) << 11) + (s0 >> 1);
            uw[di]        = dA;
            uw[di + 4096] = dB;                                        // nk+2: +2*2048 dwords
        }
    }
}

// ---------------- block-wide sum over 256 threads ----------------
__device__ __forceinline__ float block_sum(float v, float* red, int tid) {
    #pragma unroll
    for (int off = 32; off; off >>= 1) v += __shfl_down(v, off, 64);
    if ((tid & 63) == 0) red[tid >> 6] = v;
    __syncthreads();
    const float r = (red[0] + red[1]) + (red[2] + red[3]);
    __syncthreads();
    return r;
}

// ---------------- K2: c-mix + collapsed routing. block = (m 0..7, nk 0..127) ----------------
// bx = m*128 + nk : the 8 m-blocks of one nk share an XCD; per-XCD bf16 u set = 2 MB (half an L2).
__global__ void __launch_bounds__(256) k_route(const float* __restrict__ wsc,
                                               const float* __restrict__ W,
                                               float* __restrict__ out) {
    const int tid = threadIdx.x;
    const int nk  = blockIdx.x & 127;
    const int m   = blockIdx.x >> 7;
    const int n   = nk >> 4, k = nk & 15;
    __shared__ float wl[16];
    __shared__ float red[4];
    if (tid < 16) wl[tid] = W[m*256 + tid*16 + k];
    __syncthreads();

    // softmax over b (redundant per thread; LDS broadcasts)
    float c[16], mx = -1e30f;
    #pragma unroll
    for (int b = 0; b < 16; ++b) { c[b] = wl[b]; mx = fmaxf(mx, c[b]); }
    float sum = 0.f;
    #pragma unroll
    for (int b = 0; b < 16; ++b) { c[b] = __expf(c[b] - mx); sum += c[b]; }
    const float inv = 1.f / sum;
    #pragma unroll
    for (int b = 0; b < 16; ++b) c[b] *= inv;

    float sv[16], Uv[16];
    #pragma unroll
    for (int j = 0; j < 16; ++j) { sv[j] = 0.f; Uv[j] = 0.f; }
    const uint16_t* ub = (const uint16_t*)(wsc + WS_U) + ((size_t)nk << 12) + (tid << 4);
    for (int b = 0; b < 16; ++b) {
        const uint16_t* p16 = ub + ((size_t)b << 19);     // b stride = 128*4096 elems
        const uint4 va = *(const uint4*)(p16);
        const uint4 vb = *(const uint4*)(p16 + 8);
        float uv[16];
        uv[0]=BFLO(va.x);  uv[1]=BFHI(va.x);  uv[2]=BFLO(va.y);  uv[3]=BFHI(va.y);
        uv[4]=BFLO(va.z);  uv[5]=BFHI(va.z);  uv[6]=BFLO(va.w);  uv[7]=BFHI(va.w);
        uv[8]=BFLO(vb.x);  uv[9]=BFHI(vb.x);  uv[10]=BFLO(vb.y); uv[11]=BFHI(vb.y);
        uv[12]=BFLO(vb.z); uv[13]=BFHI(vb.z); uv[14]=BFLO(vb.w); uv[15]=BFHI(vb.w);
        const float cb_ = c[b];
        #pragma unroll
        for (int j = 0; j < 16; ++j) {
            Uv[j] += uv[j];
            sv[j]  = fmaf(cb_, uv[j], sv[j]);
        }
    }

    float p = 0.f;
    #pragma unroll
    for (int j = 0; j < 16; ++j) p = fmaf(sv[j], sv[j], p);
    const float n0 = block_sum(p, red, tid);
    const float r0 = __fsqrt_rn(n0) / (1.f + n0);

    float s1[16];
    p = 0.f;
    #pragma unroll
    for (int j = 0; j < 16; ++j) {
        s1[j] = sv[j] * fmaf(r0*sv[j], Uv[j], 1.f);
        p = fmaf(s1[j], s1[j], p);
    }
    const float n1 = block_sum(p, red, tid);
    const float r1 = __fsqrt_rn(n1) / (1.f + n1);

    p = 0.f;
    #pragma unroll
    for (int j = 0; j < 16; ++j) {
        s1[j] = fmaf(r1*s1[j]*s1[j], Uv[j], sv[j]);   // reuse as s2
        p = fmaf(s1[j], s1[j], p);
    }
    const float n2 = block_sum(p, red, tid);
    const float r2 = __fsqrt_rn(n2) / (1.f + n2);

    float4* po = (float4*)(out + ((size_t)((m*16 + k)*8 + n) << 12) + (tid << 4));
    #pragma unroll
    for (int q = 0; q < 4; ++q)
        po[q] = make_float4(s1[4*q+0]*r2, s1[4*q+1]*r2, s1[4*q+2]*r2, s1[4*q+3]*r2);
}

extern "C" void kernel_launch(void* const* d_in, const int* in_sizes, int n_in,
                              void* d_out, int out_size, void* d_ws, size_t ws_size,
                              hipStream_t stream) {
    const float* x      = (const float*)d_in[0];
    const float* conv_w = (const float*)d_in[1];
    const float* conv_b = (const float*)d_in[2];
    const float* caps_w = (const float*)d_in[3];
    const float* caps_b = (const float*)d_in[4];
    const float* W      = (const float*)d_in[5];
    float* ws  = (float*)d_ws;
    float* out = (float*)d_out;

    hipLaunchKernelGGL(k_cw,    dim3(128),  dim3(256), 0, stream, caps_w, conv_w, conv_b, caps_b, ws);
    hipLaunchKernelGGL(k_conv,  dim3(512),  dim3(256), 0, stream, x, ws, ws);
    hipLaunchKernelGGL(k_route, dim3(1024), dim3(256), 0, stream, ws, W, out);
}

// Round 3
// 101.169 us; speedup vs baseline: 1.2048x; 1.0575x over previous
//
#include <hip/hip_runtime.h>
#include <hip/hip_bf16.h>
#include <stdint.h>

// Problem constants: B=IC=16, L=4096, OC=256, NC=8, CD=16, K=9
#define IK_ 144
typedef __fp16 h2    __attribute__((ext_vector_type(2)));
typedef __fp16 f16x8 __attribute__((ext_vector_type(8)));
typedef float  f32x4 __attribute__((ext_vector_type(4)));

// workspace layout (float/dword element offsets)
#define WS_CWH 0u          // folded conv->caps weights, fp16 [128 nk][160 k'] (k'=i*10+t, t=9 pad=0): 10240 dwords
#define WS_CB  10240u      // cb[128] fp32
#define WS_U   10368u      // u[b][nk][s] bf16 at ((uint16_t*)(ws+WS_U)) + ((b*128+nk)<<12)+s (16.7 MB)

__device__ __forceinline__ uint32_t pack2bf(float a, float b) {
    const uint32_t lo = (uint32_t)__bfloat16_as_ushort(__float2bfloat16(a));
    const uint32_t hi = (uint32_t)__bfloat16_as_ushort(__float2bfloat16(b));
    return lo | (hi << 16);
}
#define BFLO(u) __uint_as_float((u) << 16)
#define BFHI(u) __uint_as_float((u) & 0xffff0000u)

// ---------------- K0: folded conv->caps weights, fp16 [nk][k'=i*10+t] (t=9 zero pad) ----------------
// cw[nk,i*9+t] = sum_c caps_w[nk,c]*conv_w[c,i*9+t]
// R3: full unroll (deep load pipelining; was ILP-4 on a 1-wave/SIMD grid), direct register->fp16
// store (no cwf LDS round-trip), bias fold wave-parallel (was 1 thread x 256 serial global loads).
// Summation order of the main fold is IDENTICAL to R2 (4 interleaved accumulators).
__global__ void __launch_bounds__(256) k_cw(const float* __restrict__ caps_w,
                                            const float* __restrict__ conv_w,
                                            const float* __restrict__ conv_b,
                                            const float* __restrict__ caps_b,
                                            float* __restrict__ ws) {
    __shared__ float cwl[256];
    const int nk  = blockIdx.x;
    const int tid = threadIdx.x;
    cwl[tid] = caps_w[nk*256 + tid];
    __syncthreads();

    if (tid < IK_) {
        float a0 = 0.f, a1 = 0.f, a2 = 0.f, a3 = 0.f;
        #pragma unroll
        for (int c = 0; c < 256; c += 4) {
            a0 = fmaf(cwl[c+0], conv_w[(c+0)*IK_ + tid], a0);
            a1 = fmaf(cwl[c+1], conv_w[(c+1)*IK_ + tid], a1);
            a2 = fmaf(cwl[c+2], conv_w[(c+2)*IK_ + tid], a2);
            a3 = fmaf(cwl[c+3], conv_w[(c+3)*IK_ + tid], a3);
        }
        const float a = (a0 + a1) + (a2 + a3);
        const int i = tid / 9, t = tid - 9*i;          // ik = i*9 + t  ->  k' = i*10 + t
        ((uint16_t*)(ws + WS_CWH))[nk*160 + i*10 + t] = __builtin_bit_cast(uint16_t, (__fp16)a);
    } else if (tid < 160) {
        ((uint16_t*)(ws + WS_CWH))[nk*160 + (tid - IK_)*10 + 9] = (uint16_t)0;  // t=9 pad taps
    }

    if ((tid >> 6) == 3) {                             // wave 3: bias fold, coalesced + shuffle-reduce
        const int l = tid & 63;
        float s = 0.f;
        #pragma unroll
        for (int j = 0; j < 4; ++j) {
            const int c = (l << 2) + j;
            s = fmaf(cwl[c], conv_b[c], s);
        }
        #pragma unroll
        for (int off = 32; off; off >>= 1) s += __shfl_down(s, off, 64);
        if (l == 0) ws[WS_CB + nk] = s + caps_b[nk];
    }
}

// ---------------- K1: u[b,nk,s] via MFMA f32_16x16x32_f16 ----------------
// block = (b 0..15 | stile 0..31), 128 s per tile, all 128 nk per block.
// 4 waves, 2x2: wave tile = 64 nk x 64 s = 4x4 fragments of 16x16. K'=160 = 5 k-steps of 32.
// A = weights from LDS (row stride 168 halves, bank-spread). B built per-lane from raw x window
// (scalar LDS f32 reads + cvt_pkrtz) -- no im2col materialization.
__global__ void __launch_bounds__(256) k_conv(const float* __restrict__ x,
                                              const float* __restrict__ wsc,
                                              float* __restrict__ ws) {
    const int tid   = threadIdx.x;
    const int b     = blockIdx.x & 15;
    const int stile = blockIdx.x >> 4;
    const int sbase = stile << 7;

    __shared__ float  xs[16*140];      // row i, elem e <-> x[b,i, sbase-4+e], e in [0,137), OOB = 0
    __shared__ __fp16 aw[128*168];     // [nk][k'] padded row stride 168
    __shared__ float  cbl[128];

    // stage folded weights: 128 rows x 320 B; half-row (80 halves = 10 uint4) per thread
    {
        const int row = tid >> 1, hf = tid & 1;
        const uint4* src = (const uint4*)((const uint16_t*)(wsc + WS_CWH) + row*160 + hf*80);
        uint4* dst = (uint4*)(aw + row*168 + hf*80);
        #pragma unroll
        for (int j = 0; j < 10; ++j) dst[j] = src[j];
    }
    if (tid < 128) cbl[tid] = wsc[WS_CB + tid];

    // stage x window [sbase-4, sbase+136): 16 rows x 35 float4 (divide-free, zero OOB)
    {
        const int row = tid >> 4, c0 = tid & 15;
        const float* xr = x + (b << 16) + (row << 12);
        float* lr = xs + row*140;
        #pragma unroll
        for (int k3 = 0; k3 < 3; ++k3) {
            const int col = c0 + (k3 << 4);
            if (col < 35) {
                const int j0 = sbase - 4 + (col << 2);
                float4 v;
                if (j0 < 0 || j0 > 4092) v = make_float4(0.f, 0.f, 0.f, 0.f);
                else v = *(const float4*)(xr + j0);
                *(float4*)(lr + (col << 2)) = v;
            }
        }
    }
    __syncthreads();

    const int lane = tid & 63;
    const int wid  = tid >> 6;
    const int sub  = lane & 15;     // A-row / B-col within fragment
    const int g    = lane >> 4;     // k-chunk group (8 k each)
    const int wm   = wid >> 1;      // nk half (0,1)
    const int wn   = wid & 1;       // s half (0,1)

    f32x4 acc[4][4] = {};

    #pragma unroll
    for (int kb = 0; kb < 5; ++kb) {
        // A fragments: 8 contiguous halves per lane from row (nk), offset kb*32 + g*8
        f16x8 a[4];
        #pragma unroll
        for (int mi = 0; mi < 4; ++mi)
            a[mi] = *(const f16x8*)(aw + ((wm<<6) + (mi<<4) + sub)*168 + (kb<<5) + (g<<3));

        // per-lane x_lds offsets for this lane's 8 k' values (k' = i*10 + t)
        int offs[8];
        #pragma unroll
        for (int e = 0; e < 8; ++e) {
            const int kp = (kb<<5) + (g<<3) + e;
            const int i  = kp / 10;
            offs[e] = i*140 + (kp - 10*i);   // xs elem e = s_local + t
        }

        // B fragments: read 8 f32 from raw x window, pack to fp16 pairs (RTZ, same as old path)
        f16x8 bf[4];
        #pragma unroll
        for (int ni = 0; ni < 4; ++ni) {
            const int sl = (wn<<6) + (ni<<4) + sub;
            float f[8];
            #pragma unroll
            for (int e = 0; e < 8; ++e) f[e] = xs[offs[e] + sl];
            union { h2 h[4]; f16x8 v; } u;
            u.h[0] = __builtin_amdgcn_cvt_pkrtz(f[0], f[1]);
            u.h[1] = __builtin_amdgcn_cvt_pkrtz(f[2], f[3]);
            u.h[2] = __builtin_amdgcn_cvt_pkrtz(f[4], f[5]);
            u.h[3] = __builtin_amdgcn_cvt_pkrtz(f[6], f[7]);
            bf[ni] = u.v;
        }

        #pragma unroll
        for (int mi = 0; mi < 4; ++mi) {
            #pragma unroll
            for (int ni = 0; ni < 4; ++ni)
                acc[mi][ni] = __builtin_amdgcn_mfma_f32_16x16x32_f16(a[mi], bf[ni], acc[mi][ni], 0, 0, 0);
        }
    }

    // epilogue: C/D layout col(s)=lane&15, row(nk)=g*4+reg. Pair s-adjacent lanes via shfl_xor(1)
    // so each lane stores one bf16x2 dword (even lane -> rows j0/j2, odd lane -> rows j1/j3).
    // Consecutive ni fragments fill complete 128B lines per nk row -> write-combines cleanly.
    const int odd = sub & 1;
    uint32_t* uw = (uint32_t*)((uint16_t*)(ws + WS_U));
    #pragma unroll
    for (int mi = 0; mi < 4; ++mi) {
        const int nkb = (wm<<6) + (mi<<4) + (g<<2);
        const float cb0 = cbl[nkb+0], cb1 = cbl[nkb+1], cb2 = cbl[nkb+2], cb3 = cbl[nkb+3];
        #pragma unroll
        for (int ni = 0; ni < 4; ++ni) {
            const f32x4 v = acc[mi][ni];
            const uint32_t A01 = pack2bf(v.x + cb0, v.y + cb1);
            const uint32_t A23 = pack2bf(v.z + cb2, v.w + cb3);
            const uint32_t Q01 = (uint32_t)__shfl_xor((int)A01, 1);
            const uint32_t Q23 = (uint32_t)__shfl_xor((int)A23, 1);
            const uint32_t dA = odd ? ((Q01 >> 16) | (A01 & 0xffff0000u))
                                    : ((A01 & 0xffffu) | (Q01 << 16));
            const uint32_t dB = odd ? ((Q23 >> 16) | (A23 & 0xffff0000u))
                                    : ((A23 & 0xffffu) | (Q23 << 16));
            const int nkA = nkb + odd;                                 // row j0 or j1 (dB: +2)
            const int s0  = sbase + (wn<<6) + (ni<<4) + (sub & ~1);
            const size_t di = (((size_t)((b<<7) + nkA)) << 11) + (s0 >> 1);
            uw[di]        = dA;
            uw[di + 4096] = dB;                                        // nk+2: +2*2048 dwords
        }
    }
}

// ---------------- block-wide sum over 256 threads ----------------
__device__ __forceinline__ float block_sum(float v, float* red, int tid) {
    #pragma unroll
    for (int off = 32; off; off >>= 1) v += __shfl_down(v, off, 64);
    if ((tid & 63) == 0) red[tid >> 6] = v;
    __syncthreads();
    const float r = (red[0] + red[1]) + (red[2] + red[3]);
    __syncthreads();
    return r;
}

// ---------------- K2: c-mix + collapsed routing. block = (m 0..7, nk 0..127) ----------------
// bx = m*128 + nk : the 8 m-blocks of one nk share an XCD; per-XCD bf16 u set = 2 MB (half an L2).
__global__ void __launch_bounds__(256) k_route(const float* __restrict__ wsc,
                                               const float* __restrict__ W,
                                               float* __restrict__ out) {
    const int tid = threadIdx.x;
    const int nk  = blockIdx.x & 127;
    const int m   = blockIdx.x >> 7;
    const int n   = nk >> 4, k = nk & 15;
    __shared__ float wl[16];
    __shared__ float red[4];
    if (tid < 16) wl[tid] = W[m*256 + tid*16 + k];
    __syncthreads();

    // softmax over b (redundant per thread; LDS broadcasts)
    float c[16], mx = -1e30f;
    #pragma unroll
    for (int b = 0; b < 16; ++b) { c[b] = wl[b]; mx = fmaxf(mx, c[b]); }
    float sum = 0.f;
    #pragma unroll
    for (int b = 0; b < 16; ++b) { c[b] = __expf(c[b] - mx); sum += c[b]; }
    const float inv = 1.f / sum;
    #pragma unroll
    for (int b = 0; b < 16; ++b) c[b] *= inv;

    float sv[16], Uv[16];
    #pragma unroll
    for (int j = 0; j < 16; ++j) { sv[j] = 0.f; Uv[j] = 0.f; }
    const uint16_t* ub = (const uint16_t*)(wsc + WS_U) + ((size_t)nk << 12) + (tid << 4);
    for (int b = 0; b < 16; ++b) {
        const uint16_t* p16 = ub + ((size_t)b << 19);     // b stride = 128*4096 elems
        const uint4 va = *(const uint4*)(p16);
        const uint4 vb = *(const uint4*)(p16 + 8);
        float uv[16];
        uv[0]=BFLO(va.x);  uv[1]=BFHI(va.x);  uv[2]=BFLO(va.y);  uv[3]=BFHI(va.y);
        uv[4]=BFLO(va.z);  uv[5]=BFHI(va.z);  uv[6]=BFLO(va.w);  uv[7]=BFHI(va.w);
        uv[8]=BFLO(vb.x);  uv[9]=BFHI(vb.x);  uv[10]=BFLO(vb.y); uv[11]=BFHI(vb.y);
        uv[12]=BFLO(vb.z); uv[13]=BFHI(vb.z); uv[14]=BFLO(vb.w); uv[15]=BFHI(vb.w);
        const float cb_ = c[b];
        #pragma unroll
        for (int j = 0; j < 16; ++j) {
            Uv[j] += uv[j];
            sv[j]  = fmaf(cb_, uv[j], sv[j]);
        }
    }

    float p = 0.f;
    #pragma unroll
    for (int j = 0; j < 16; ++j) p = fmaf(sv[j], sv[j], p);
    const float n0 = block_sum(p, red, tid);
    const float r0 = __fsqrt_rn(n0) / (1.f + n0);

    float s1[16];
    p = 0.f;
    #pragma unroll
    for (int j = 0; j < 16; ++j) {
        s1[j] = sv[j] * fmaf(r0*sv[j], Uv[j], 1.f);
        p = fmaf(s1[j], s1[j], p);
    }
    const float n1 = block_sum(p, red, tid);
    const float r1 = __fsqrt_rn(n1) / (1.f + n1);

    p = 0.f;
    #pragma unroll
    for (int j = 0; j < 16; ++j) {
        s1[j] = fmaf(r1*s1[j]*s1[j], Uv[j], sv[j]);   // reuse as s2
        p = fmaf(s1[j], s1[j], p);
    }
    const float n2 = block_sum(p, red, tid);
    const float r2 = __fsqrt_rn(n2) / (1.f + n2);

    float4* po = (float4*)(out + ((size_t)((m*16 + k)*8 + n) << 12) + (tid << 4));
    #pragma unroll
    for (int q = 0; q < 4; ++q)
        po[q] = make_float4(s1[4*q+0]*r2, s1[4*q+1]*r2, s1[4*q+2]*r2, s1[4*q+3]*r2);
}

extern "C" void kernel_launch(void* const* d_in, const int* in_sizes, int n_in,
                              void* d_out, int out_size, void* d_ws, size_t ws_size,
                              hipStream_t stream) {
    const float* x      = (const float*)d_in[0];
    const float* conv_w = (const float*)d_in[1];
    const float* conv_b = (const float*)d_in[2];
    const float* caps_w = (const float*)d_in[3];
    const float* caps_b = (const float*)d_in[4];
    const float* W      = (const float*)d_in[5];
    float* ws  = (float*)d_ws;
    float* out = (float*)d_out;

    hipLaunchKernelGGL(k_cw,    dim3(128),  dim3(256), 0, stream, caps_w, conv_w, conv_b, caps_b, ws);
    hipLaunchKernelGGL(k_conv,  dim3(512),  dim3(256), 0, stream, x, ws, ws);
    hipLaunchKernelGGL(k_route, dim3(1024), dim3(256), 0, stream, ws, W, out);
}